// Round 1
// baseline (479.134 us; speedup 1.0000x reference)
//
#include <hip/hip_runtime.h>
#include <hip/hip_bf16.h>

// SO3Linear: out[b,m,o] = sum_i x[b,m,i] * (W[l(m),o,i] - 1/sqrt(128)), bias on m=0.
// Strategy: bf16 MFMA (16x16x32), fp32 accumulate. Grid (64 batch-chunks, 25 m).
// Each block: one m (one weight matrix), 256 batch rows. B-fragments held in
// registers for the whole block (32 frags = 128 VGPRs); A streamed from global.
// Memory-bound: ~420 MB total HBM traffic -> ~67 us floor at 6.3 TB/s.

#define BATCH 16384
#define NUM_M 25
#define NF 128
#define BB 64                       // batch-chunks per m
#define ROWS_PER_BLOCK (BATCH / BB) // 256
#define TILE_ROWS 64                // 4 waves x 16 rows

typedef __attribute__((ext_vector_type(8))) short short8;   // 8 bf16 (4 VGPRs)
typedef __attribute__((ext_vector_type(4))) float floatx4;  // MFMA C/D

// fp32 -> bf16, round-to-nearest-even (inputs finite; no NaN handling needed)
__device__ inline short f2bf(float f) {
    union { float f; unsigned u; } v;
    v.f = f;
    unsigned r = v.u + 0x7fffu + ((v.u >> 16) & 1u);
    return (short)(r >> 16);
}

__global__ __launch_bounds__(256, 2)
void so3_mfma_kernel(const float* __restrict__ x,
                     const float* __restrict__ w,
                     const float* __restrict__ bias,
                     float* __restrict__ out) {
    const int m = blockIdx.y;
    const int l = (m >= 16) ? 4 : (m >= 9) ? 3 : (m >= 4) ? 2 : (m >= 1) ? 1 : 0;
    const int wave = threadIdx.x >> 6;
    const int lane = threadIdx.x & 63;
    const int q    = lane >> 4;   // 0..3
    const int n16  = lane & 15;   // 0..15
    const float bound = 0.08838834764831843f; // 1/sqrt(128)

    // ---- B fragments (centered weights), kept in registers for whole block ----
    // B-operand lane layout: col n = lane&15, k = q*8 + j (j=0..7) per 32-wide k-chunk.
    // B[k][n] = Wc[l][o=n][i=k] -> lane reads 8 contiguous i of weight row o. 
    short8 bfrag[8][4];
    {
        const float* wl = w + l * NF * NF;
        #pragma unroll
        for (int nt = 0; nt < 8; ++nt) {
            const int o = nt * 16 + n16;
            #pragma unroll
            for (int kc = 0; kc < 4; ++kc) {
                const int k = kc * 32 + q * 8;
                const floatx4* p = (const floatx4*)(wl + o * NF + k);
                floatx4 w0 = p[0], w1 = p[1];
                short8 f;
                f[0] = f2bf(w0[0] - bound); f[1] = f2bf(w0[1] - bound);
                f[2] = f2bf(w0[2] - bound); f[3] = f2bf(w0[3] - bound);
                f[4] = f2bf(w1[0] - bound); f[5] = f2bf(w1[1] - bound);
                f[6] = f2bf(w1[2] - bound); f[7] = f2bf(w1[3] - bound);
                bfrag[nt][kc] = f;
            }
        }
    }

    // bias applies only to m==0 rows (branch is block-uniform)
    float bvals[8];
    #pragma unroll
    for (int nt = 0; nt < 8; ++nt)
        bvals[nt] = (m == 0) ? bias[nt * 16 + n16] : 0.0f;

    const int b0 = blockIdx.x * ROWS_PER_BLOCK;

    for (int it = 0; it < ROWS_PER_BLOCK / TILE_ROWS; ++it) {
        const int rowb = b0 + it * TILE_ROWS + wave * 16; // batch base of 16-row tile

        // ---- A fragments: lane holds x[rowb + n16][kc*32 + q*8 .. +8] ----
        short8 a[4];
        {
            const int bA = rowb + n16;
            const float* xr = x + (bA * NUM_M + m) * NF;
            #pragma unroll
            for (int kc = 0; kc < 4; ++kc) {
                const int k = kc * 32 + q * 8;
                const floatx4* p = (const floatx4*)(xr + k);
                floatx4 x0 = p[0], x1 = p[1];
                short8 f;
                f[0] = f2bf(x0[0]); f[1] = f2bf(x0[1]);
                f[2] = f2bf(x0[2]); f[3] = f2bf(x0[3]);
                f[4] = f2bf(x1[0]); f[5] = f2bf(x1[1]);
                f[6] = f2bf(x1[2]); f[7] = f2bf(x1[3]);
                a[kc] = f;
            }
        }

        // ---- MFMA: 8 independent acc chains, 4 k-steps each ----
        floatx4 acc[8] = {};
        #pragma unroll
        for (int nt = 0; nt < 8; ++nt) {
            #pragma unroll
            for (int kc = 0; kc < 4; ++kc) {
                acc[nt] = __builtin_amdgcn_mfma_f32_16x16x32_bf16(
                    a[kc], bfrag[nt][kc], acc[nt], 0, 0, 0);
            }
        }

        // ---- store: C/D layout col = lane&15, row = q*4 + reg ----
        #pragma unroll
        for (int nt = 0; nt < 8; ++nt) {
            #pragma unroll
            for (int r = 0; r < 4; ++r) {
                const int brow = rowb + q * 4 + r;
                out[(brow * NUM_M + m) * NF + nt * 16 + n16] = acc[nt][r] + bvals[nt];
            }
        }
    }
}

extern "C" void kernel_launch(void* const* d_in, const int* in_sizes, int n_in,
                              void* d_out, int out_size, void* d_ws, size_t ws_size,
                              hipStream_t stream) {
    const float* x    = (const float*)d_in[0]; // [16384, 25, 128]
    const float* w    = (const float*)d_in[1]; // [5, 128, 128]
    const float* bias = (const float*)d_in[2]; // [128]
    float* out = (float*)d_out;                // [16384, 25, 128]

    dim3 grid(BB, NUM_M);
    dim3 block(256);
    so3_mfma_kernel<<<grid, block, 0, stream>>>(x, w, bias, out);
}